// Round 5
// baseline (229.523 us; speedup 1.0000x reference)
//
#include <hip/hip_runtime.h>
#include <hip/hip_bf16.h>
#include <stdint.h>

typedef __hip_bfloat16 bf16;
typedef __attribute__((ext_vector_type(8))) short short8;   // 8 bf16
typedef __attribute__((ext_vector_type(4))) float f32x4;

#define QSCALE 0.18033688011f   // 0.125 * log2(e), folded into Q at gemm0

// ---- 1-instr helpers ----
__device__ __forceinline__ float fast_exp2(float x) {
#if __has_builtin(__builtin_amdgcn_exp2f)
  return __builtin_amdgcn_exp2f(x);
#else
  return exp2f(x);
#endif
}

__device__ __forceinline__ uint32_t pack2_bf16(float a, float b) {
#if __has_builtin(__builtin_amdgcn_cvt_pk_bf16_f32)
  typedef __attribute__((ext_vector_type(2))) __bf16 bf16x2;
  bf16x2 v = __builtin_amdgcn_cvt_pk_bf16_f32(a, b);
  return __builtin_bit_cast(uint32_t, v);
#else
  uint32_t ua = __builtin_bit_cast(uint32_t, a);
  uint32_t ub = __builtin_bit_cast(uint32_t, b);
  ua += 0x7FFF + ((ua >> 16) & 1);   // RNE
  ub += 0x7FFF + ((ub >> 16) & 1);
  return (ua >> 16) | (ub & 0xFFFF0000u);
#endif
}

// async global->LDS, 16B per lane, LDS dest = wave-uniform base + lane*16
__device__ __forceinline__ void gload_lds16(const bf16* g, bf16* l) {
#if __has_builtin(__builtin_amdgcn_global_load_lds)
  __builtin_amdgcn_global_load_lds(
      (const __attribute__((address_space(1))) void*)(uintptr_t)g,
      (__attribute__((address_space(3))) void*)(uint32_t)(uintptr_t)l,
      16, 0, 0);
#else
  int lane = threadIdx.x & 63;
  *(short8*)(l + lane * 8) = *(const short8*)(g + lane * 8);
#endif
}

// LDS-only barrier (no vmcnt drain): keeps global prefetch loads in flight.
__device__ __forceinline__ void lds_barrier() {
  asm volatile("s_waitcnt lgkmcnt(0)\n\ts_barrier" ::: "memory");
}

// ---- fp32->bf16 transpose tile body (64x64) ----
__device__ __forceinline__ void transpose_tile(const float* __restrict__ in,
                                               bf16* __restrict__ out,
                                               int R, int C, int bx, int by,
                                               bf16 (*t)[72]) {
  const int r0 = by * 64, c0 = bx * 64;
  const int rr = threadIdx.x >> 3, cc = (threadIdx.x & 7) * 8;
#pragma unroll
  for (int rep = 0; rep < 2; ++rep) {
    int y = rr + rep * 32;
    const float* p = in + (size_t)(r0 + y) * C + c0 + cc;
    f32x4 v0 = *(const f32x4*)p;
    f32x4 v1 = *(const f32x4*)(p + 4);
#pragma unroll
    for (int j = 0; j < 4; ++j) {
      t[cc + j][y] = __float2bfloat16(v0[j]);
      t[cc + 4 + j][y] = __float2bfloat16(v1[j]);
    }
  }
  __syncthreads();
#pragma unroll
  for (int rep = 0; rep < 2; ++rep) {
    int y = rr + rep * 32;
    short8 v = *(const short8*)&t[y][cc];
    *(short8*)(out + (size_t)(c0 + y) * R + r0 + cc) = v;
  }
}

// ---- fused prep: x->bf16 (blocks 0..2047), Wqkv^T (2048..2815),
//      Wproj^T (2816..3071) ----
__global__ __launch_bounds__(256)
void prep_k(const float* __restrict__ x, bf16* __restrict__ xb,
            const float* __restrict__ Wqkv, bf16* __restrict__ WtQkv,
            const float* __restrict__ Wproj, bf16* __restrict__ WtP) {
  __shared__ __align__(16) bf16 t[64][72];
  const int bid = blockIdx.x;
  if (bid < 2048) {
    int i = (bid * 256 + threadIdx.x) * 8;
    f32x4 v0 = *(const f32x4*)(x + i);
    f32x4 v1 = *(const f32x4*)(x + i + 4);
    short8 r;
    bf16* rb = (bf16*)&r;
#pragma unroll
    for (int j = 0; j < 4; ++j) {
      rb[j] = __float2bfloat16(v0[j]);
      rb[4 + j] = __float2bfloat16(v1[j]);
    }
    *(short8*)(xb + i) = r;
  } else if (bid < 2048 + 768) {
    int b = bid - 2048;
    transpose_tile(Wqkv, WtQkv, 1024, 3072, b % 48, b / 48, t);
  } else {
    int b = bid - 2816;
    transpose_tile(Wproj, WtP, 1024, 1024, b % 16, b / 16, t);
  }
}

// ---------------- GEMM: C[m][n] = A[m,:]·Bt[n,:] + bias[n] -------------------
// MODE 0 (TM=128): LDS-transposed coalesced epilogue -> Q (xQSCALE) / K as
//                  [bh][t][64], V^T as [bh][64][t]. All 16B/lane stores.
// MODE 1 (TM=64):  fp32 out row-major [M,Nn].
template <int MODE, int TM>
__global__ __launch_bounds__(256, 2)
void gemm_bt(const bf16* __restrict__ A, const bf16* __restrict__ Bt,
             const float* __restrict__ bias, float* __restrict__ outp,
             bf16* __restrict__ Qd, bf16* __restrict__ Kd, bf16* __restrict__ Vt,
             int M, int Nn, int K) {
  constexpr int MI = TM / 32;
  // staging (TM*32 + 4096 el) and MODE-0 epilogue (<=9216 el) share this pool
  __shared__ __align__(16) bf16 smem[(TM == 128) ? 9216 : 6144];
  bf16* As = smem;
  bf16* Bs = smem + TM * 32;

  const int tid = threadIdx.x;
  const int wave = tid >> 6, lane = tid & 63;
  const int quad = lane >> 4, l16 = lane & 15;
  const int mw = (wave >> 1) * (TM / 2), nw = (wave & 1) * 64;
  const int m_blk = blockIdx.y * TM, n_blk = blockIdx.x * 128;

  f32x4 acc[MI][4];
#pragma unroll
  for (int i = 0; i < MI; ++i)
#pragma unroll
    for (int j = 0; j < 4; ++j) acc[i][j] = (f32x4){0.f, 0.f, 0.f, 0.f};

  const int rowA = lane >> 2, colA = (lane & 3) * 8;
  const int chunkB = wave * 2;
  const bf16* gB = Bt + (size_t)(n_blk + chunkB * 16 + rowA) * K + colA;
  bf16* lB0 = &Bs[chunkB * 16 * 32];
  bf16* lB1 = &Bs[(chunkB + 1) * 16 * 32];

  const int chunkA = (TM == 128) ? wave * 2 : wave;
  const bf16* gA = A + (size_t)(m_blk + chunkA * 16 + rowA) * K + colA;
  bf16* lA0 = &As[chunkA * 16 * 32];
  bf16* lA1 = &As[(chunkA + 1) * 16 * 32];  // unused for TM=64

  for (int kt = 0; kt < K; kt += 32) {
    gload_lds16(gA, lA0);
    if (TM == 128) gload_lds16(gA + 16 * K, lA1);
    gload_lds16(gB, lB0);
    gload_lds16(gB + 16 * K, lB1);
    gA += 32; gB += 32;
    __syncthreads();
    short8 af[MI], bfv[4];
#pragma unroll
    for (int i = 0; i < MI; ++i)
      af[i] = *(const short8*)&As[(mw + i * 16 + l16) * 32 + quad * 8];
#pragma unroll
    for (int j = 0; j < 4; ++j)
      bfv[j] = *(const short8*)&Bs[(nw + j * 16 + l16) * 32 + quad * 8];
#pragma unroll
    for (int i = 0; i < MI; ++i)
#pragma unroll
      for (int j = 0; j < 4; ++j)
        acc[i][j] = __builtin_amdgcn_mfma_f32_16x16x32_bf16(af[i], bfv[j],
                                                            acc[i][j], 0, 0, 0);
    __syncthreads();
  }

  if (MODE == 0) {
    // per-j bias for this wave's columns
    float bval[4];
#pragma unroll
    for (int j = 0; j < 4; ++j) bval[j] = bias[n_blk + nw + j * 16 + l16];

    const int part = n_blk >> 10;          // 0:q 1:k 2:v (block-uniform)
    const int b = m_blk >> 11;
    const int tloc = m_blk & 2047;
    const int h0 = (n_blk & 1023) >> 6;

#pragma unroll
    for (int p = 0; p < 2; ++p) {          // feature halves (64 cols = 1 head)
      __syncthreads();
      if ((nw >> 6) == p) {
        if (part == 2) {
          // V half-tile as [64 d][136 t], 8B-packed writes (r -> t contiguous)
#pragma unroll
          for (int i = 0; i < MI; ++i)
#pragma unroll
            for (int j = 0; j < 4; ++j) {
              const int dh = j * 16 + l16;
              const int t0 = mw + i * 16 + quad * 4;
              uint2 pk;
              pk.x = pack2_bf16(acc[i][j][0] + bval[j], acc[i][j][1] + bval[j]);
              pk.y = pack2_bf16(acc[i][j][2] + bval[j], acc[i][j][3] + bval[j]);
              *(uint2*)&smem[dh * 136 + t0] = pk;
            }
        } else {
          // Q/K half-tile as [128 t][72 d] (stride-72: conflict-free writes)
          const float sc = (part == 0) ? QSCALE : 1.0f;
#pragma unroll
          for (int i = 0; i < MI; ++i)
#pragma unroll
            for (int j = 0; j < 4; ++j) {
              const int d = j * 16 + l16;
              const int t0 = mw + i * 16 + quad * 4;
#pragma unroll
              for (int r = 0; r < 4; ++r)
                smem[(t0 + r) * 72 + d] =
                    __float2bfloat16((acc[i][j][r] + bval[j]) * sc);
            }
        }
      }
      __syncthreads();
      const size_t bh = (size_t)(b * 16 + h0 + p);
      if (part == 2) {
#pragma unroll
        for (int it = 0; it < 4; ++it) {
          const int dl = (tid >> 4) + it * 16;
          const int t8 = (tid & 15) * 8;
          short8 v = *(const short8*)&smem[dl * 136 + t8];
          *(short8*)&Vt[(bh * 64 + dl) * 2048 + tloc + t8] = v;
        }
      } else {
        bf16* dst = (part == 0) ? Qd : Kd;
#pragma unroll
        for (int it = 0; it < 4; ++it) {
          const int row = (tid >> 3) + it * 32;
          const int col8 = (tid & 7) * 8;
          short8 v = *(const short8*)&smem[row * 72 + col8];
          *(short8*)&dst[(bh * 2048 + tloc + row) * 64 + col8] = v;
        }
      }
    }
  } else {
#pragma unroll
    for (int j = 0; j < 4; ++j) {
      const int ncol = n_blk + nw + j * 16 + l16;
      const float bval = bias[ncol];
#pragma unroll
      for (int i = 0; i < MI; ++i) {
        const int mrow0 = m_blk + mw + i * 16 + quad * 4;
#pragma unroll
        for (int r = 0; r < 4; ++r)
          outp[(size_t)(mrow0 + r) * Nn + ncol] = acc[i][j][r] + bval;
      }
    }
  }
}

// ---------------- flash attention: Qtile=64, KVtile=64, quadrant split -------
// Wave (qh,kvh) owns q-half x kv-half. Structure = R3's pi-permuted PV, with
// two LDS-traffic cuts:
//  * K NEVER touches LDS: fragments load straight from global (16 rows x 64B
//    = dense L2 transactions), reloaded 1 tile ahead into the same regs.
//  * V is stored PI-INTERLEAVED in LDS: within each 32-kv half, kv bits
//    (hi,q,e) are stored at position (q<<3)|(hi<<2)|e, so each PV B-fragment
//    is ONE b128 read at [d][kvh*32 + quad*8] (bank-uniform via the 72-pad).
//    Stage writes become 4 x b64 per thread (2-way, free).
// Row-sums via ones-MFMA (no VALU adds, no epilogue shuffle). V double-
// buffered in 18432 B; ONE lds_barrier per iteration; 4 blocks/CU.
__global__ __launch_bounds__(256, 4)
void attn_kernel(const bf16* __restrict__ Qg, const bf16* __restrict__ Kg,
                 const bf16* __restrict__ Vt, bf16* __restrict__ yg) {
  // [0,18432): Vts[2][64][72]. Epilogue reuse: red 16384 B + sred 256 B.
  __shared__ __align__(16) char pool[18432];
  bf16* VtsB = (bf16*)pool;

  const int tid = threadIdx.x;
  const int wave = tid >> 6, lane = tid & 63;
  const int quad = lane >> 4, l16 = lane & 15;
  const int qh = wave & 1, kvh = wave >> 1;

  const int bx = blockIdx.x;
  const int qt = bx & 31;                // 32 q-tiles of 64
  const int bh = bx >> 5;                // b*16 + h

  const bf16* Qb = Qg + ((size_t)bh * 2048 + qt * 64) * 64;
  const bf16* Kb = Kg + (size_t)bh * 2048 * 64;
  const bf16* Vtb = Vt + (size_t)bh * 64 * 2048;

  // Q fragments (pre-scaled by QSCALE at gemm0)
  short8 qf[2][2];
#pragma unroll
  for (int qblk = 0; qblk < 2; ++qblk)
#pragma unroll
    for (int ks = 0; ks < 2; ++ks)
      qf[qblk][ks] = *(const short8*)(
          Qb + (size_t)(qh * 32 + qblk * 16 + l16) * 64 + ks * 32 + quad * 8);

  // V staging addressing: thread covers row vdd, global chunks vo and vo+4.
  const int vdd = tid & 63, vo = tid >> 6;
  const bf16* Vp = Vtb + (size_t)vdd * 2048 + vo * 8;
  // interleave: global chunk c -> LDS cols bcol(c), bcol(c)+8 (b64 each)
  const int bcol0 = ((vo >> 2) << 5) | ((vo & 1) << 4) | ((vo & 2) << 1);
  const int vc1 = vo + 4;
  const int bcol1 = ((vc1 >> 2) << 5) | ((vc1 & 1) << 4) | ((vc1 & 2) << 1);

  // K fragment pointer: row kvh*32 + kvblk*16 + l16, col ks*32 + quad*8
  const bf16* KpF = Kb + (size_t)(kvh * 32 + l16) * 64 + quad * 8;

  // preamble: V tile0 -> LDS buf0 (interleaved); V tile1 -> regs;
  //           K tile0 -> regs
  short8 kf[2][2];
  {
    short8 c0 = *(const short8*)Vp;
    short8 c1 = *(const short8*)(Vp + 32);
    uint4 u0 = __builtin_bit_cast(uint4, c0);
    uint4 u1 = __builtin_bit_cast(uint4, c1);
    *(uint2*)(VtsB + vdd * 72 + bcol0) = (uint2){u0.x, u0.y};
    *(uint2*)(VtsB + vdd * 72 + bcol0 + 8) = (uint2){u0.z, u0.w};
    *(uint2*)(VtsB + vdd * 72 + bcol1) = (uint2){u1.x, u1.y};
    *(uint2*)(VtsB + vdd * 72 + bcol1 + 8) = (uint2){u1.z, u1.w};
  }
  short8 gv0 = *(const short8*)(Vp + 64);
  short8 gv1 = *(const short8*)(Vp + 96);
#pragma unroll
  for (int kvblk = 0; kvblk < 2; ++kvblk)
#pragma unroll
    for (int ks = 0; ks < 2; ++ks)
      kf[kvblk][ks] =
          *(const short8*)(KpF + (size_t)(kvblk * 16) * 64 + ks * 32);
  __syncthreads();

  f32x4 yacc[2][4];
#pragma unroll
  for (int qblk = 0; qblk < 2; ++qblk)
#pragma unroll
    for (int dblk = 0; dblk < 4; ++dblk)
      yacc[qblk][dblk] = (f32x4){0.f, 0.f, 0.f, 0.f};
  f32x4 sum_acc[2];
  sum_acc[0] = (f32x4){0.f, 0.f, 0.f, 0.f};
  sum_acc[1] = (f32x4){0.f, 0.f, 0.f, 0.f};

  uint4 ones_u;
  ones_u.x = ones_u.y = ones_u.z = ones_u.w = 0x3F803F80u;  // bf16 1.0 x8
  const short8 ones8 = __builtin_bit_cast(short8, ones_u);

  // per-wave V fragment read offsets: one b128 per dblk
  int vro[4];
#pragma unroll
  for (int dblk = 0; dblk < 4; ++dblk)
    vro[dblk] = (dblk * 16 + l16) * 72 + kvh * 32 + quad * 8;

  for (int kt = 0; kt < 2048; kt += 64) {
    const int cur = (kt >> 6) & 1;
    bf16* VtsC = VtsB + cur * 4608;

    // 1. V fragments for this iteration (single b128 each, pi-interleaved)
    short8 vb8[4];
#pragma unroll
    for (int dblk = 0; dblk < 4; ++dblk)
      vb8[dblk] = *(const short8*)(VtsC + vro[dblk]);

    // 2. commit V tile kt+64 into other buffer; prefetch V kt+128
    if (kt + 64 < 2048) {
      bf16* VtsN = VtsB + (cur ^ 1) * 4608;
      uint4 u0 = __builtin_bit_cast(uint4, gv0);
      uint4 u1 = __builtin_bit_cast(uint4, gv1);
      *(uint2*)(VtsN + vdd * 72 + bcol0) = (uint2){u0.x, u0.y};
      *(uint2*)(VtsN + vdd * 72 + bcol0 + 8) = (uint2){u0.z, u0.w};
      *(uint2*)(VtsN + vdd * 72 + bcol1) = (uint2){u1.x, u1.y};
      *(uint2*)(VtsN + vdd * 72 + bcol1 + 8) = (uint2){u1.z, u1.w};
      if (kt + 128 < 2048) {
        gv0 = *(const short8*)(Vp + kt + 128);
        gv1 = *(const short8*)(Vp + kt + 128 + 32);
      }
    }

    // 3. S^T from current K regs, then reload K for kt+64 (global, dense L2)
    f32x4 s0[2], s1[2];
#pragma unroll
    for (int qblk = 0; qblk < 2; ++qblk) {
      f32x4 a0 = (f32x4){0.f, 0.f, 0.f, 0.f};
      f32x4 a1 = (f32x4){0.f, 0.f, 0.f, 0.f};
      a0 = __builtin_amdgcn_mfma_f32_16x16x32_bf16(kf[0][0], qf[qblk][0], a0, 0, 0, 0);
      a0 = __builtin_amdgcn_mfma_f32_16x16x32_bf16(kf[0][1], qf[qblk][1], a0, 0, 0, 0);
      a1 = __builtin_amdgcn_mfma_f32_16x16x32_bf16(kf[1][0], qf[qblk][0], a1, 0, 0, 0);
      a1 = __builtin_amdgcn_mfma_f32_16x16x32_bf16(kf[1][1], qf[qblk][1], a1, 0, 0, 0);
      s0[qblk] = a0;
      s1[qblk] = a1;
    }
    if (kt + 64 < 2048) {
      const bf16* kp = KpF + (size_t)(kt + 64) * 64;
#pragma unroll
      for (int kvblk = 0; kvblk < 2; ++kvblk)
#pragma unroll
        for (int ks = 0; ks < 2; ++ks)
          kf[kvblk][ks] =
              *(const short8*)(kp + (size_t)(kvblk * 16) * 64 + ks * 32);
    }

    // 4. softmax -> pa8 (registers, pi k-slot order); row-sum via ones-MFMA
    short8 pa8[2];
#pragma unroll
    for (int qblk = 0; qblk < 2; ++qblk) {
      float p0 = fast_exp2(s0[qblk][0]), p1 = fast_exp2(s0[qblk][1]);
      float p2 = fast_exp2(s0[qblk][2]), p3 = fast_exp2(s0[qblk][3]);
      float p4 = fast_exp2(s1[qblk][0]), p5 = fast_exp2(s1[qblk][1]);
      float p6 = fast_exp2(s1[qblk][2]), p7 = fast_exp2(s1[qblk][3]);
      uint4 u;
      u.x = pack2_bf16(p0, p1);
      u.y = pack2_bf16(p2, p3);
      u.z = pack2_bf16(p4, p5);
      u.w = pack2_bf16(p6, p7);
      pa8[qblk] = __builtin_bit_cast(short8, u);
      sum_acc[qblk] = __builtin_amdgcn_mfma_f32_16x16x32_bf16(
          pa8[qblk], ones8, sum_acc[qblk], 0, 0, 0);
    }

    // 5. Y += P·V (K=32 MFMA, single-b128 V fragments)
#pragma unroll
    for (int dblk = 0; dblk < 4; ++dblk) {
      yacc[0][dblk] = __builtin_amdgcn_mfma_f32_16x16x32_bf16(
          pa8[0], vb8[dblk], yacc[0][dblk], 0, 0, 0);
      yacc[1][dblk] = __builtin_amdgcn_mfma_f32_16x16x32_bf16(
          pa8[1], vb8[dblk], yacc[1][dblk], 0, 0, 0);
    }

    // 6. single barrier: V reads done + V commits visible
    lds_barrier();
  }

  // ---- epilogue: reduce kv-halves across waves (sums ride in sum_acc) ----
  __syncthreads();
  float* red = (float*)pool;                 // 16384 B Y-partials
  float* sred = (float*)(pool + 16384);      // 256 B sums
  if (kvh == 1) {
#pragma unroll
    for (int qblk = 0; qblk < 2; ++qblk) {
#pragma unroll
      for (int dblk = 0; dblk < 4; ++dblk) {
        const int f = (qh * 2 + qblk) * 4 + dblk;
        *(f32x4*)&red[(f * 64 + quad * 16 + l16) * 4] = yacc[qblk][dblk];
      }
      if (l16 == 0)
        *(f32x4*)&sred[(qh * 2 + qblk) * 16 + quad * 4] = sum_acc[qblk];
    }
  }
  __syncthreads();
  if (kvh == 0) {
    const int b = bh >> 4, h = bh & 15;
    const size_t rowbase = (size_t)b * 2048 + qt * 64;
#pragma unroll
    for (int qblk = 0; qblk < 2; ++qblk) {
      f32x4 sp = *(const f32x4*)&sred[(qh * 2 + qblk) * 16 + quad * 4];
#pragma unroll
      for (int dblk = 0; dblk < 4; ++dblk) {
        const int f = (qh * 2 + qblk) * 4 + dblk;
        f32x4 o = *(const f32x4*)&red[(f * 64 + quad * 16 + l16) * 4];
#pragma unroll
        for (int r = 0; r < 4; ++r) yacc[qblk][dblk][r] += o[r];
      }
#pragma unroll
      for (int r = 0; r < 4; ++r) {
        const float inv = 1.f / (sum_acc[qblk][r] + sp[r]);
        const int rr = qh * 32 + qblk * 16 + quad * 4 + r;
#pragma unroll
        for (int dblk = 0; dblk < 4; ++dblk)
          yg[(rowbase + rr) * 1024 + h * 64 + dblk * 16 + l16] =
              __float2bfloat16(yacc[qblk][dblk][r] * inv);
      }
    }
  }
}

// ---------------- launch ----------------
extern "C" void kernel_launch(void* const* d_in, const int* in_sizes, int n_in,
                              void* d_out, int out_size, void* d_ws, size_t ws_size,
                              hipStream_t stream) {
  const float* x = (const float*)d_in[0];      // [4096, 1024] fp32
  const float* Wqkv = (const float*)d_in[1];   // [1024, 3072] fp32
  const float* bqkv = (const float*)d_in[2];   // [3072] fp32
  const float* Wproj = (const float*)d_in[3];  // [1024, 1024] fp32
  const float* bproj = (const float*)d_in[4];  // [1024] fp32
  float* out = (float*)d_out;                  // [4096, 1024] fp32

  if (ws_size < (size_t)40 * 1024 * 1024) return;

  char* ws = (char*)d_ws;
  bf16* xb    = (bf16*)(ws + 0);             // [4096,1024] = 8 MiB
  bf16* yd    = (bf16*)(ws + 0);             // aliases xb (dead after gemm0)
  bf16* WtQkv = (bf16*)(ws + 8388608);       // [3072,1024] = 6 MiB
  bf16* WtP   = (bf16*)(ws + 14680064);      // [1024,1024] = 2 MiB
  bf16* Qd    = (bf16*)(ws + 16777216);      // [32,2048,64] = 8 MiB (pre-scaled)
  bf16* Kd    = (bf16*)(ws + 25165824);      // 8 MiB
  bf16* Vten  = (bf16*)(ws + 33554432);      // [32,64,2048] = 8 MiB

  prep_k<<<3072, 256, 0, stream>>>(x, xb, Wqkv, WtQkv, Wproj, WtP);
  gemm_bt<0, 128><<<dim3(24, 32), 256, 0, stream>>>(
      xb, WtQkv, bqkv, nullptr, Qd, Kd, Vten, 4096, 3072, 1024);
  attn_kernel<<<dim3(1024), 256, 0, stream>>>(Qd, Kd, Vten, yd);
  gemm_bt<1, 64><<<dim3(8, 64), 256, 0, stream>>>(
      yd, WtP, bproj, out, nullptr, nullptr, nullptr, 4096, 1024, 1024);
}

// Round 6
// 225.703 us; speedup vs baseline: 1.0169x; 1.0169x over previous
//
#include <hip/hip_runtime.h>
#include <hip/hip_bf16.h>
#include <stdint.h>

typedef __hip_bfloat16 bf16;
typedef __attribute__((ext_vector_type(8))) short short8;   // 8 bf16
typedef __attribute__((ext_vector_type(4))) float f32x4;

#define QSCALE 0.18033688011f   // 0.125 * log2(e), folded into Q at gemm0

// ---- 1-instr helpers ----
__device__ __forceinline__ float fast_exp2(float x) {
#if __has_builtin(__builtin_amdgcn_exp2f)
  return __builtin_amdgcn_exp2f(x);
#else
  return exp2f(x);
#endif
}

__device__ __forceinline__ uint32_t pack2_bf16(float a, float b) {
#if __has_builtin(__builtin_amdgcn_cvt_pk_bf16_f32)
  typedef __attribute__((ext_vector_type(2))) __bf16 bf16x2;
  bf16x2 v = __builtin_amdgcn_cvt_pk_bf16_f32(a, b);
  return __builtin_bit_cast(uint32_t, v);
#else
  uint32_t ua = __builtin_bit_cast(uint32_t, a);
  uint32_t ub = __builtin_bit_cast(uint32_t, b);
  ua += 0x7FFF + ((ua >> 16) & 1);   // RNE
  ub += 0x7FFF + ((ub >> 16) & 1);
  return (ua >> 16) | (ub & 0xFFFF0000u);
#endif
}

// async global->LDS, 16B per lane, LDS dest = wave-uniform base + lane*16
__device__ __forceinline__ void gload_lds16(const bf16* g, bf16* l) {
#if __has_builtin(__builtin_amdgcn_global_load_lds)
  __builtin_amdgcn_global_load_lds(
      (const __attribute__((address_space(1))) void*)(uintptr_t)g,
      (__attribute__((address_space(3))) void*)(uint32_t)(uintptr_t)l,
      16, 0, 0);
#else
  int lane = threadIdx.x & 63;
  *(short8*)(l + lane * 8) = *(const short8*)(g + lane * 8);
#endif
}

// LDS-only barrier (no vmcnt drain): keeps global prefetch loads in flight.
__device__ __forceinline__ void lds_barrier() {
  asm volatile("s_waitcnt lgkmcnt(0)\n\ts_barrier" ::: "memory");
}

// ---- fp32->bf16 transpose tile body (64x64) ----
__device__ __forceinline__ void transpose_tile(const float* __restrict__ in,
                                               bf16* __restrict__ out,
                                               int R, int C, int bx, int by,
                                               bf16 (*t)[72]) {
  const int r0 = by * 64, c0 = bx * 64;
  const int rr = threadIdx.x >> 3, cc = (threadIdx.x & 7) * 8;
#pragma unroll
  for (int rep = 0; rep < 2; ++rep) {
    int y = rr + rep * 32;
    const float* p = in + (size_t)(r0 + y) * C + c0 + cc;
    f32x4 v0 = *(const f32x4*)p;
    f32x4 v1 = *(const f32x4*)(p + 4);
#pragma unroll
    for (int j = 0; j < 4; ++j) {
      t[cc + j][y] = __float2bfloat16(v0[j]);
      t[cc + 4 + j][y] = __float2bfloat16(v1[j]);
    }
  }
  __syncthreads();
#pragma unroll
  for (int rep = 0; rep < 2; ++rep) {
    int y = rr + rep * 32;
    short8 v = *(const short8*)&t[y][cc];
    *(short8*)(out + (size_t)(c0 + y) * R + r0 + cc) = v;
  }
}

// ---- fused prep: x->bf16 (blocks 0..2047), Wqkv^T (2048..2815),
//      Wproj^T (2816..3071) ----
__global__ __launch_bounds__(256)
void prep_k(const float* __restrict__ x, bf16* __restrict__ xb,
            const float* __restrict__ Wqkv, bf16* __restrict__ WtQkv,
            const float* __restrict__ Wproj, bf16* __restrict__ WtP) {
  __shared__ __align__(16) bf16 t[64][72];
  const int bid = blockIdx.x;
  if (bid < 2048) {
    int i = (bid * 256 + threadIdx.x) * 8;
    f32x4 v0 = *(const f32x4*)(x + i);
    f32x4 v1 = *(const f32x4*)(x + i + 4);
    short8 r;
    bf16* rb = (bf16*)&r;
#pragma unroll
    for (int j = 0; j < 4; ++j) {
      rb[j] = __float2bfloat16(v0[j]);
      rb[4 + j] = __float2bfloat16(v1[j]);
    }
    *(short8*)(xb + i) = r;
  } else if (bid < 2048 + 768) {
    int b = bid - 2048;
    transpose_tile(Wqkv, WtQkv, 1024, 3072, b % 48, b / 48, t);
  } else {
    int b = bid - 2816;
    transpose_tile(Wproj, WtP, 1024, 1024, b % 16, b / 16, t);
  }
}

// ---------------- GEMM: C[m][n] = A[m,:]·Bt[n,:] + bias[n] -------------------
// MODE 0 (TM=128): LDS-transposed coalesced epilogue -> Q (xQSCALE) / K as
//                  [bh][t][64], V^T as [bh][64][t]. All 16B/lane stores.
// MODE 1 (TM=64):  fp32 out row-major [M,Nn].
template <int MODE, int TM>
__global__ __launch_bounds__(256, 2)
void gemm_bt(const bf16* __restrict__ A, const bf16* __restrict__ Bt,
             const float* __restrict__ bias, float* __restrict__ outp,
             bf16* __restrict__ Qd, bf16* __restrict__ Kd, bf16* __restrict__ Vt,
             int M, int Nn, int K) {
  constexpr int MI = TM / 32;
  // staging (TM*32 + 4096 el) and MODE-0 epilogue (<=9216 el) share this pool
  __shared__ __align__(16) bf16 smem[(TM == 128) ? 9216 : 6144];
  bf16* As = smem;
  bf16* Bs = smem + TM * 32;

  const int tid = threadIdx.x;
  const int wave = tid >> 6, lane = tid & 63;
  const int quad = lane >> 4, l16 = lane & 15;
  const int mw = (wave >> 1) * (TM / 2), nw = (wave & 1) * 64;
  const int m_blk = blockIdx.y * TM, n_blk = blockIdx.x * 128;

  f32x4 acc[MI][4];
#pragma unroll
  for (int i = 0; i < MI; ++i)
#pragma unroll
    for (int j = 0; j < 4; ++j) acc[i][j] = (f32x4){0.f, 0.f, 0.f, 0.f};

  const int rowA = lane >> 2, colA = (lane & 3) * 8;
  const int chunkB = wave * 2;
  const bf16* gB = Bt + (size_t)(n_blk + chunkB * 16 + rowA) * K + colA;
  bf16* lB0 = &Bs[chunkB * 16 * 32];
  bf16* lB1 = &Bs[(chunkB + 1) * 16 * 32];

  const int chunkA = (TM == 128) ? wave * 2 : wave;
  const bf16* gA = A + (size_t)(m_blk + chunkA * 16 + rowA) * K + colA;
  bf16* lA0 = &As[chunkA * 16 * 32];
  bf16* lA1 = &As[(chunkA + 1) * 16 * 32];  // unused for TM=64

  for (int kt = 0; kt < K; kt += 32) {
    gload_lds16(gA, lA0);
    if (TM == 128) gload_lds16(gA + 16 * K, lA1);
    gload_lds16(gB, lB0);
    gload_lds16(gB + 16 * K, lB1);
    gA += 32; gB += 32;
    __syncthreads();
    short8 af[MI], bfv[4];
#pragma unroll
    for (int i = 0; i < MI; ++i)
      af[i] = *(const short8*)&As[(mw + i * 16 + l16) * 32 + quad * 8];
#pragma unroll
    for (int j = 0; j < 4; ++j)
      bfv[j] = *(const short8*)&Bs[(nw + j * 16 + l16) * 32 + quad * 8];
#pragma unroll
    for (int i = 0; i < MI; ++i)
#pragma unroll
      for (int j = 0; j < 4; ++j)
        acc[i][j] = __builtin_amdgcn_mfma_f32_16x16x32_bf16(af[i], bfv[j],
                                                            acc[i][j], 0, 0, 0);
    __syncthreads();
  }

  if (MODE == 0) {
    // per-j bias for this wave's columns
    float bval[4];
#pragma unroll
    for (int j = 0; j < 4; ++j) bval[j] = bias[n_blk + nw + j * 16 + l16];

    const int part = n_blk >> 10;          // 0:q 1:k 2:v (block-uniform)
    const int b = m_blk >> 11;
    const int tloc = m_blk & 2047;
    const int h0 = (n_blk & 1023) >> 6;

#pragma unroll
    for (int p = 0; p < 2; ++p) {          // feature halves (64 cols = 1 head)
      __syncthreads();
      if ((nw >> 6) == p) {
        if (part == 2) {
          // V half-tile as [64 d][136 t], 8B-packed writes (r -> t contiguous)
#pragma unroll
          for (int i = 0; i < MI; ++i)
#pragma unroll
            for (int j = 0; j < 4; ++j) {
              const int dh = j * 16 + l16;
              const int t0 = mw + i * 16 + quad * 4;
              uint2 pk;
              pk.x = pack2_bf16(acc[i][j][0] + bval[j], acc[i][j][1] + bval[j]);
              pk.y = pack2_bf16(acc[i][j][2] + bval[j], acc[i][j][3] + bval[j]);
              *(uint2*)&smem[dh * 136 + t0] = pk;
            }
        } else {
          // Q/K half-tile as [128 t][72 d] (stride-72: conflict-free writes)
          const float sc = (part == 0) ? QSCALE : 1.0f;
#pragma unroll
          for (int i = 0; i < MI; ++i)
#pragma unroll
            for (int j = 0; j < 4; ++j) {
              const int d = j * 16 + l16;
              const int t0 = mw + i * 16 + quad * 4;
#pragma unroll
              for (int r = 0; r < 4; ++r)
                smem[(t0 + r) * 72 + d] =
                    __float2bfloat16((acc[i][j][r] + bval[j]) * sc);
            }
        }
      }
      __syncthreads();
      const size_t bh = (size_t)(b * 16 + h0 + p);
      if (part == 2) {
#pragma unroll
        for (int it = 0; it < 4; ++it) {
          const int dl = (tid >> 4) + it * 16;
          const int t8 = (tid & 15) * 8;
          short8 v = *(const short8*)&smem[dl * 136 + t8];
          *(short8*)&Vt[(bh * 64 + dl) * 2048 + tloc + t8] = v;
        }
      } else {
        bf16* dst = (part == 0) ? Qd : Kd;
#pragma unroll
        for (int it = 0; it < 4; ++it) {
          const int row = (tid >> 3) + it * 32;
          const int col8 = (tid & 7) * 8;
          short8 v = *(const short8*)&smem[row * 72 + col8];
          *(short8*)&dst[(bh * 2048 + tloc + row) * 64 + col8] = v;
        }
      }
    }
  } else {
#pragma unroll
    for (int j = 0; j < 4; ++j) {
      const int ncol = n_blk + nw + j * 16 + l16;
      const float bval = bias[ncol];
#pragma unroll
      for (int i = 0; i < MI; ++i) {
        const int mrow0 = m_blk + mw + i * 16 + quad * 4;
#pragma unroll
        for (int r = 0; r < 4; ++r)
          outp[(size_t)(mrow0 + r) * Nn + ncol] = acc[i][j][r] + bval;
      }
    }
  }
}

// ---------------- flash attention: Qtile=32, KVtile=128, kv-slice waves ------
// Wave w owns kv rows [w*32, w*32+32) x ALL 32 q of this block -> ZERO
// cross-wave duplication of K/V fragment reads (R3 read everything twice).
// S^T = K·Q^T per 16-kv subtile: lane (quad,l16) holds S[q=l16][kv=quad*4+r];
// the two subtiles concatenate into the 16x16x32 A-fragment under k-slot
// permutation pi(quad*8+e) = {quad*4+e (e<4), 16+quad*4+e-4 (e>=4)}. V is
// read with the SAME pi (two b64s), keeping PV at full K=32 rate with P
// entirely in registers. Row-sums via ones-MFMA. K/V SINGLE-buffered
// (35840 B -> 4 blocks/CU by LDS) with next tile prefetched to registers;
// commit after the mid-iteration barrier (R0's proven pattern). 2 barriers
// per 128 kv = same rate as R3 at -33% LDS traffic per kv.
__global__ __launch_bounds__(256, 3)
void attn_kernel(const bf16* __restrict__ Qg, const bf16* __restrict__ Kg,
                 const bf16* __restrict__ Vt, bf16* __restrict__ yg) {
  // [0,18432): Ks[128][72]; [18432,35840): Vts[64][136].
  // Epilogue reuse: 3 slots x 8320 B (8192 yacc + 128 sums) = 24960 B.
  __shared__ __align__(16) char pool[35840];
  bf16* Ks = (bf16*)pool;
  bf16* Vts = (bf16*)(pool + 18432);

  const int tid = threadIdx.x;
  const int wave = tid >> 6, lane = tid & 63;   // wave = kv slice (32 rows)
  const int quad = lane >> 4, l16 = lane & 15;

  const int bx = blockIdx.x;
  const int qt = bx & 63;                // 64 q-tiles of 32
  const int bh = bx >> 6;                // b*16 + h

  const bf16* Qb = Qg + ((size_t)bh * 2048 + qt * 32) * 64;
  const bf16* Kb = Kg + (size_t)bh * 2048 * 64;
  const bf16* Vtb = Vt + (size_t)bh * 64 * 2048;

  // Q fragments: 32 q rows, same for all waves (pre-scaled at gemm0)
  short8 qf[2][2];
#pragma unroll
  for (int qblk = 0; qblk < 2; ++qblk)
#pragma unroll
    for (int ks = 0; ks < 2; ++ks)
      qf[qblk][ks] = *(const short8*)(
          Qb + (size_t)(qblk * 16 + l16) * 64 + ks * 32 + quad * 8);

  // staging addressing (block-cooperative, coalesced global reads)
  const int kr = tid >> 3, kc = (tid & 7) * 8;   // K: rows kr+32j, j=0..3
  const int vdd = tid & 63, vo = tid >> 6;       // V: d row, chunks vo+4j
  const bf16* Kp = Kb + (size_t)kr * 64 + kc;    // + (kt + 32j)*64
  const bf16* Vp = Vtb + (size_t)vdd * 2048 + vo * 8;  // + kt + j*32
  int vws[4];
#pragma unroll
  for (int j = 0; j < 4; ++j)
    vws[j] = vdd * 136 + (((vo + 4 * j) + (vdd >> 3)) & 15) * 8;

  // preamble: tile0 -> LDS; tile1 -> regs
#pragma unroll
  for (int j = 0; j < 4; ++j) {
    short8 a = *(const short8*)(Kp + (size_t)(32 * j) * 64);
    *(short8*)(Ks + (kr + 32 * j) * 72 + kc) = a;
  }
#pragma unroll
  for (int j = 0; j < 4; ++j) {
    short8 c = *(const short8*)(Vp + j * 32);
    *(short8*)(Vts + vws[j]) = c;
  }
  short8 gk[4], gv[4];
#pragma unroll
  for (int j = 0; j < 4; ++j)
    gk[j] = *(const short8*)(Kp + (size_t)(128 + 32 * j) * 64);
#pragma unroll
  for (int j = 0; j < 4; ++j)
    gv[j] = *(const short8*)(Vp + 128 + j * 32);
  __syncthreads();

  f32x4 yacc[2][4];
#pragma unroll
  for (int qblk = 0; qblk < 2; ++qblk)
#pragma unroll
    for (int dblk = 0; dblk < 4; ++dblk)
      yacc[qblk][dblk] = (f32x4){0.f, 0.f, 0.f, 0.f};
  f32x4 sum_acc[2];
  sum_acc[0] = (f32x4){0.f, 0.f, 0.f, 0.f};
  sum_acc[1] = (f32x4){0.f, 0.f, 0.f, 0.f};

  uint4 ones_u;
  ones_u.x = ones_u.y = ones_u.z = ones_u.w = 0x3F803F80u;  // bf16 1.0 x8
  const short8 ones8 = __builtin_bit_cast(short8, ones_u);

  // per-wave fragment LDS offsets (element units)
  const int kfo = (wave * 32 + l16) * 72 + quad * 8;  // + kvblk*16*72 + ks*32
  int vbo[4][2];                                      // b64 reads, pi-permuted
#pragma unroll
  for (int dblk = 0; dblk < 4; ++dblk) {
    const int d = dblk * 16 + l16;
#pragma unroll
    for (int kvblk = 0; kvblk < 2; ++kvblk) {
      const int c = wave * 4 + kvblk * 2 + (quad >> 1);  // t-chunk 0..15
      vbo[dblk][kvblk] = d * 136 + ((c + (d >> 3)) & 15) * 8 + (quad & 1) * 4;
    }
  }

  for (int kt = 0; kt < 2048; kt += 128) {
    // 1. fragment reads from the single buffer
    short8 kf[2][2];
#pragma unroll
    for (int kvblk = 0; kvblk < 2; ++kvblk)
#pragma unroll
      for (int ks = 0; ks < 2; ++ks)
        kf[kvblk][ks] =
            *(const short8*)(Ks + kfo + kvblk * 16 * 72 + ks * 32);
    short8 vb8[4];
#pragma unroll
    for (int dblk = 0; dblk < 4; ++dblk) {
      uint2 lo = *(const uint2*)(Vts + vbo[dblk][0]);
      uint2 hi = *(const uint2*)(Vts + vbo[dblk][1]);
      uint4 u;
      u.x = lo.x; u.y = lo.y; u.z = hi.x; u.w = hi.y;
      vb8[dblk] = __builtin_bit_cast(short8, u);
    }

    // 2. barrier: all waves' reads landed -> buffer reusable
    lds_barrier();

    // 3. commit prefetched tile kt+128; prefetch kt+256 into the same regs
    if (kt + 128 < 2048) {
#pragma unroll
      for (int j = 0; j < 4; ++j)
        *(short8*)(Ks + (kr + 32 * j) * 72 + kc) = gk[j];
#pragma unroll
      for (int j = 0; j < 4; ++j)
        *(short8*)(Vts + vws[j]) = gv[j];
      if (kt + 256 < 2048) {
#pragma unroll
        for (int j = 0; j < 4; ++j)
          gk[j] = *(const short8*)(Kp + (size_t)(kt + 256 + 32 * j) * 64);
#pragma unroll
        for (int j = 0; j < 4; ++j)
          gv[j] = *(const short8*)(Vp + kt + 256 + j * 32);
      }
    }

    // 4. S^T + softmax -> pa8; row-sum via ones-MFMA (hides ds_write latency)
    short8 pa8[2];
#pragma unroll
    for (int qblk = 0; qblk < 2; ++qblk) {
      f32x4 s0 = (f32x4){0.f, 0.f, 0.f, 0.f};
      f32x4 s1 = (f32x4){0.f, 0.f, 0.f, 0.f};
      s0 = __builtin_amdgcn_mfma_f32_16x16x32_bf16(kf[0][0], qf[qblk][0], s0, 0, 0, 0);
      s0 = __builtin_amdgcn_mfma_f32_16x16x32_bf16(kf[0][1], qf[qblk][1], s0, 0, 0, 0);
      s1 = __builtin_amdgcn_mfma_f32_16x16x32_bf16(kf[1][0], qf[qblk][0], s1, 0, 0, 0);
      s1 = __builtin_amdgcn_mfma_f32_16x16x32_bf16(kf[1][1], qf[qblk][1], s1, 0, 0, 0);
      float p0 = fast_exp2(s0[0]), p1 = fast_exp2(s0[1]);
      float p2 = fast_exp2(s0[2]), p3 = fast_exp2(s0[3]);
      float p4 = fast_exp2(s1[0]), p5 = fast_exp2(s1[1]);
      float p6 = fast_exp2(s1[2]), p7 = fast_exp2(s1[3]);
      uint4 u;
      u.x = pack2_bf16(p0, p1);
      u.y = pack2_bf16(p2, p3);
      u.z = pack2_bf16(p4, p5);
      u.w = pack2_bf16(p6, p7);
      pa8[qblk] = __builtin_bit_cast(short8, u);
      sum_acc[qblk] = __builtin_amdgcn_mfma_f32_16x16x32_bf16(
          pa8[qblk], ones8, sum_acc[qblk], 0, 0, 0);
    }

    // 5. Y += P·V (K=32 MFMA, pi-permuted V fragments)
#pragma unroll
    for (int dblk = 0; dblk < 4; ++dblk) {
      yacc[0][dblk] = __builtin_amdgcn_mfma_f32_16x16x32_bf16(
          pa8[0], vb8[dblk], yacc[0][dblk], 0, 0, 0);
      yacc[1][dblk] = __builtin_amdgcn_mfma_f32_16x16x32_bf16(
          pa8[1], vb8[dblk], yacc[1][dblk], 0, 0, 0);
    }

    // 6. barrier: commits visible before next iteration's reads
    lds_barrier();
  }

  // ---- epilogue: single-phase reduce of the 4 kv-slice partials ----
  __syncthreads();
  float* red = (float*)pool;   // 3 slots x 2080 floats (2048 yacc + 32 sums)
  if (wave != 0) {
    float* buf = red + (wave - 1) * 2080;
#pragma unroll
    for (int qblk = 0; qblk < 2; ++qblk) {
#pragma unroll
      for (int dblk = 0; dblk < 4; ++dblk)
        *(f32x4*)&buf[((qblk * 4 + dblk) * 64 + lane) * 4] = yacc[qblk][dblk];
      if (l16 == 0)
        *(f32x4*)&buf[2048 + qblk * 16 + quad * 4] = sum_acc[qblk];
    }
  }
  __syncthreads();
  if (wave == 0) {
#pragma unroll
    for (int w = 0; w < 3; ++w) {
      float* buf = red + w * 2080;
#pragma unroll
      for (int qblk = 0; qblk < 2; ++qblk) {
        f32x4 sp = *(const f32x4*)&buf[2048 + qblk * 16 + quad * 4];
#pragma unroll
        for (int r = 0; r < 4; ++r) sum_acc[qblk][r] += sp[r];
#pragma unroll
        for (int dblk = 0; dblk < 4; ++dblk) {
          f32x4 o = *(const f32x4*)&buf[((qblk * 4 + dblk) * 64 + lane) * 4];
#pragma unroll
          for (int r = 0; r < 4; ++r) yacc[qblk][dblk][r] += o[r];
        }
      }
    }
    const int b = bh >> 4, h = bh & 15;
    const size_t rowbase = (size_t)b * 2048 + qt * 32;
#pragma unroll
    for (int qblk = 0; qblk < 2; ++qblk) {
#pragma unroll
      for (int r = 0; r < 4; ++r) {
        const float inv = 1.f / sum_acc[qblk][r];
        const int rr = qblk * 16 + quad * 4 + r;
#pragma unroll
        for (int dblk = 0; dblk < 4; ++dblk)
          yg[(rowbase + rr) * 1024 + h * 64 + dblk * 16 + l16] =
              __float2bfloat16(yacc[qblk][dblk][r] * inv);
      }
    }
  }
}

// ---------------- launch ----------------
extern "C" void kernel_launch(void* const* d_in, const int* in_sizes, int n_in,
                              void* d_out, int out_size, void* d_ws, size_t ws_size,
                              hipStream_t stream) {
  const float* x = (const float*)d_in[0];      // [4096, 1024] fp32
  const float* Wqkv = (const float*)d_in[1];   // [1024, 3072] fp32
  const float* bqkv = (const float*)d_in[2];   // [3072] fp32
  const float* Wproj = (const float*)d_in[3];  // [1024, 1024] fp32
  const float* bproj = (const float*)d_in[4];  // [1024] fp32
  float* out = (float*)d_out;                  // [4096, 1024] fp32

  if (ws_size < (size_t)40 * 1024 * 1024) return;

  char* ws = (char*)d_ws;
  bf16* xb    = (bf16*)(ws + 0);             // [4096,1024] = 8 MiB
  bf16* yd    = (bf16*)(ws + 0);             // aliases xb (dead after gemm0)
  bf16* WtQkv = (bf16*)(ws + 8388608);       // [3072,1024] = 6 MiB
  bf16* WtP   = (bf16*)(ws + 14680064);      // [1024,1024] = 2 MiB
  bf16* Qd    = (bf16*)(ws + 16777216);      // [32,2048,64] = 8 MiB (pre-scaled)
  bf16* Kd    = (bf16*)(ws + 25165824);      // 8 MiB
  bf16* Vten  = (bf16*)(ws + 33554432);      // [32,64,2048] = 8 MiB

  prep_k<<<3072, 256, 0, stream>>>(x, xb, Wqkv, WtQkv, Wproj, WtP);
  gemm_bt<0, 128><<<dim3(24, 32), 256, 0, stream>>>(
      xb, WtQkv, bqkv, nullptr, Qd, Kd, Vten, 4096, 3072, 1024);
  attn_kernel<<<dim3(2048), 256, 0, stream>>>(Qd, Kd, Vten, yd);
  gemm_bt<1, 64><<<dim3(8, 64), 256, 0, stream>>>(
      yd, WtP, bproj, out, nullptr, nullptr, nullptr, 4096, 1024, 1024);
}

// Round 7
// 192.444 us; speedup vs baseline: 1.1927x; 1.1728x over previous
//
#include <hip/hip_runtime.h>
#include <hip/hip_bf16.h>
#include <stdint.h>

typedef __hip_bfloat16 bf16;
typedef __attribute__((ext_vector_type(8))) short short8;   // 8 bf16
typedef __attribute__((ext_vector_type(4))) float f32x4;

#define QSCALE 0.18033688011f   // 0.125 * log2(e), folded into Q at gemm0

// ---- 1-instr helpers ----
__device__ __forceinline__ float fast_exp2(float x) {
#if __has_builtin(__builtin_amdgcn_exp2f)
  return __builtin_amdgcn_exp2f(x);
#else
  return exp2f(x);
#endif
}

__device__ __forceinline__ uint32_t pack2_bf16(float a, float b) {
#if __has_builtin(__builtin_amdgcn_cvt_pk_bf16_f32)
  typedef __attribute__((ext_vector_type(2))) __bf16 bf16x2;
  bf16x2 v = __builtin_amdgcn_cvt_pk_bf16_f32(a, b);
  return __builtin_bit_cast(uint32_t, v);
#else
  uint32_t ua = __builtin_bit_cast(uint32_t, a);
  uint32_t ub = __builtin_bit_cast(uint32_t, b);
  ua += 0x7FFF + ((ua >> 16) & 1);   // RNE
  ub += 0x7FFF + ((ub >> 16) & 1);
  return (ua >> 16) | (ub & 0xFFFF0000u);
#endif
}

// async global->LDS, 16B per lane, LDS dest = wave-uniform base + lane*16
__device__ __forceinline__ void gload_lds16(const bf16* g, bf16* l) {
#if __has_builtin(__builtin_amdgcn_global_load_lds)
  __builtin_amdgcn_global_load_lds(
      (const __attribute__((address_space(1))) void*)(uintptr_t)g,
      (__attribute__((address_space(3))) void*)(uint32_t)(uintptr_t)l,
      16, 0, 0);
#else
  int lane = threadIdx.x & 63;
  *(short8*)(l + lane * 8) = *(const short8*)(g + lane * 8);
#endif
}

// LDS-only barrier (no vmcnt drain): keeps global prefetch loads in flight.
__device__ __forceinline__ void lds_barrier() {
  asm volatile("s_waitcnt lgkmcnt(0)\n\ts_barrier" ::: "memory");
}

// ---- fp32->bf16 transpose tile body (64x64) ----
__device__ __forceinline__ void transpose_tile(const float* __restrict__ in,
                                               bf16* __restrict__ out,
                                               int R, int C, int bx, int by,
                                               bf16 (*t)[72]) {
  const int r0 = by * 64, c0 = bx * 64;
  const int rr = threadIdx.x >> 3, cc = (threadIdx.x & 7) * 8;
#pragma unroll
  for (int rep = 0; rep < 2; ++rep) {
    int y = rr + rep * 32;
    const float* p = in + (size_t)(r0 + y) * C + c0 + cc;
    f32x4 v0 = *(const f32x4*)p;
    f32x4 v1 = *(const f32x4*)(p + 4);
#pragma unroll
    for (int j = 0; j < 4; ++j) {
      t[cc + j][y] = __float2bfloat16(v0[j]);
      t[cc + 4 + j][y] = __float2bfloat16(v1[j]);
    }
  }
  __syncthreads();
#pragma unroll
  for (int rep = 0; rep < 2; ++rep) {
    int y = rr + rep * 32;
    short8 v = *(const short8*)&t[y][cc];
    *(short8*)(out + (size_t)(c0 + y) * R + r0 + cc) = v;
  }
}

// ---- fused prep: x->bf16 (blocks 0..2047), Wqkv^T (2048..2815),
//      Wproj^T (2816..3071) ----
__global__ __launch_bounds__(256)
void prep_k(const float* __restrict__ x, bf16* __restrict__ xb,
            const float* __restrict__ Wqkv, bf16* __restrict__ WtQkv,
            const float* __restrict__ Wproj, bf16* __restrict__ WtP) {
  __shared__ __align__(16) bf16 t[64][72];
  const int bid = blockIdx.x;
  if (bid < 2048) {
    int i = (bid * 256 + threadIdx.x) * 8;
    f32x4 v0 = *(const f32x4*)(x + i);
    f32x4 v1 = *(const f32x4*)(x + i + 4);
    short8 r;
    bf16* rb = (bf16*)&r;
#pragma unroll
    for (int j = 0; j < 4; ++j) {
      rb[j] = __float2bfloat16(v0[j]);
      rb[4 + j] = __float2bfloat16(v1[j]);
    }
    *(short8*)(xb + i) = r;
  } else if (bid < 2048 + 768) {
    int b = bid - 2048;
    transpose_tile(Wqkv, WtQkv, 1024, 3072, b % 48, b / 48, t);
  } else {
    int b = bid - 2816;
    transpose_tile(Wproj, WtP, 1024, 1024, b % 16, b / 16, t);
  }
}

// ---------------- GEMM: C[m][n] = A[m,:]·Bt[n,:] + bias[n] -------------------
// MODE 0 (TM=128): LDS-transposed coalesced epilogue -> Q (xQSCALE) / K as
//                  [bh][t][64], V^T as [bh][64][t]. All 16B/lane stores.
// MODE 1 (TM=64):  fp32 out row-major [M,Nn].
// Grid is XCD-chunk swizzled (nwg % 8 == 0 in both uses -> bijective):
// each XCD gets a contiguous run of M-panels for A-reuse in its private L2.
template <int MODE, int TM>
__global__ __launch_bounds__(256, 2)
void gemm_bt(const bf16* __restrict__ A, const bf16* __restrict__ Bt,
             const float* __restrict__ bias, float* __restrict__ outp,
             bf16* __restrict__ Qd, bf16* __restrict__ Kd, bf16* __restrict__ Vt,
             int M, int Nn, int K) {
  constexpr int MI = TM / 32;
  // staging (TM*32 + 4096 el) and MODE-0 epilogue (<=9216 el) share this pool
  __shared__ __align__(16) bf16 smem[(TM == 128) ? 9216 : 6144];
  bf16* As = smem;
  bf16* Bs = smem + TM * 32;

  const int tid = threadIdx.x;
  const int wave = tid >> 6, lane = tid & 63;
  const int quad = lane >> 4, l16 = lane & 15;
  const int mw = (wave >> 1) * (TM / 2), nw = (wave & 1) * 64;

  // XCD-chunked swizzle of the linearized block id
  const int nwg = gridDim.x * gridDim.y;
  const int ord = blockIdx.y * gridDim.x + blockIdx.x;
  const int wg = (ord & 7) * (nwg >> 3) + (ord >> 3);
  const int m_blk = (wg / gridDim.x) * TM, n_blk = (wg % gridDim.x) * 128;

  f32x4 acc[MI][4];
#pragma unroll
  for (int i = 0; i < MI; ++i)
#pragma unroll
    for (int j = 0; j < 4; ++j) acc[i][j] = (f32x4){0.f, 0.f, 0.f, 0.f};

  const int rowA = lane >> 2, colA = (lane & 3) * 8;
  const int chunkB = wave * 2;
  const bf16* gB = Bt + (size_t)(n_blk + chunkB * 16 + rowA) * K + colA;
  bf16* lB0 = &Bs[chunkB * 16 * 32];
  bf16* lB1 = &Bs[(chunkB + 1) * 16 * 32];

  const int chunkA = (TM == 128) ? wave * 2 : wave;
  const bf16* gA = A + (size_t)(m_blk + chunkA * 16 + rowA) * K + colA;
  bf16* lA0 = &As[chunkA * 16 * 32];
  bf16* lA1 = &As[(chunkA + 1) * 16 * 32];  // unused for TM=64

  for (int kt = 0; kt < K; kt += 32) {
    gload_lds16(gA, lA0);
    if (TM == 128) gload_lds16(gA + 16 * K, lA1);
    gload_lds16(gB, lB0);
    gload_lds16(gB + 16 * K, lB1);
    gA += 32; gB += 32;
    __syncthreads();
    short8 af[MI], bfv[4];
#pragma unroll
    for (int i = 0; i < MI; ++i)
      af[i] = *(const short8*)&As[(mw + i * 16 + l16) * 32 + quad * 8];
#pragma unroll
    for (int j = 0; j < 4; ++j)
      bfv[j] = *(const short8*)&Bs[(nw + j * 16 + l16) * 32 + quad * 8];
#pragma unroll
    for (int i = 0; i < MI; ++i)
#pragma unroll
      for (int j = 0; j < 4; ++j)
        acc[i][j] = __builtin_amdgcn_mfma_f32_16x16x32_bf16(af[i], bfv[j],
                                                            acc[i][j], 0, 0, 0);
    __syncthreads();
  }

  if (MODE == 0) {
    // per-j bias for this wave's columns
    float bval[4];
#pragma unroll
    for (int j = 0; j < 4; ++j) bval[j] = bias[n_blk + nw + j * 16 + l16];

    const int part = n_blk >> 10;          // 0:q 1:k 2:v (block-uniform)
    const int b = m_blk >> 11;
    const int tloc = m_blk & 2047;
    const int h0 = (n_blk & 1023) >> 6;

#pragma unroll
    for (int p = 0; p < 2; ++p) {          // feature halves (64 cols = 1 head)
      __syncthreads();
      if ((nw >> 6) == p) {
        if (part == 2) {
          // V half-tile as [64 d][136 t], 8B-packed writes (r -> t contiguous)
#pragma unroll
          for (int i = 0; i < MI; ++i)
#pragma unroll
            for (int j = 0; j < 4; ++j) {
              const int dh = j * 16 + l16;
              const int t0 = mw + i * 16 + quad * 4;
              uint2 pk;
              pk.x = pack2_bf16(acc[i][j][0] + bval[j], acc[i][j][1] + bval[j]);
              pk.y = pack2_bf16(acc[i][j][2] + bval[j], acc[i][j][3] + bval[j]);
              *(uint2*)&smem[dh * 136 + t0] = pk;
            }
        } else {
          // Q/K half-tile as [128 t][72 d] (stride-72: conflict-free writes)
          const float sc = (part == 0) ? QSCALE : 1.0f;
#pragma unroll
          for (int i = 0; i < MI; ++i)
#pragma unroll
            for (int j = 0; j < 4; ++j) {
              const int d = j * 16 + l16;
              const int t0 = mw + i * 16 + quad * 4;
#pragma unroll
              for (int r = 0; r < 4; ++r)
                smem[(t0 + r) * 72 + d] =
                    __float2bfloat16((acc[i][j][r] + bval[j]) * sc);
            }
        }
      }
      __syncthreads();
      const size_t bh = (size_t)(b * 16 + h0 + p);
      if (part == 2) {
#pragma unroll
        for (int it = 0; it < 4; ++it) {
          const int dl = (tid >> 4) + it * 16;
          const int t8 = (tid & 15) * 8;
          short8 v = *(const short8*)&smem[dl * 136 + t8];
          *(short8*)&Vt[(bh * 64 + dl) * 2048 + tloc + t8] = v;
        }
      } else {
        bf16* dst = (part == 0) ? Qd : Kd;
#pragma unroll
        for (int it = 0; it < 4; ++it) {
          const int row = (tid >> 3) + it * 32;
          const int col8 = (tid & 7) * 8;
          short8 v = *(const short8*)&smem[row * 72 + col8];
          *(short8*)&dst[(bh * 2048 + tloc + row) * 64 + col8] = v;
        }
      }
    }
  } else {
#pragma unroll
    for (int j = 0; j < 4; ++j) {
      const int ncol = n_blk + nw + j * 16 + l16;
      const float bval = bias[ncol];
#pragma unroll
      for (int i = 0; i < MI; ++i) {
        const int mrow0 = m_blk + mw + i * 16 + quad * 4;
#pragma unroll
        for (int r = 0; r < 4; ++r)
          outp[(size_t)(mrow0 + r) * Nn + ncol] = acc[i][j][r] + bval;
      }
    }
  }
}

// ---------------- flash attention: Qtile=64, KVtile=64, quadrant split -------
// R3 structure (best measured): wave (qh,kvh) owns q-half x kv-half;
// S^T = K·Q^T per 16-kv subtile; the two subtiles concatenate into the
// 16x16x32 A-fragment under k-slot permutation pi; V read with the SAME pi
// (two b64s) keeps PV at full K=32 rate with P entirely in registers.
// K/V double-buffered; ONE lds_barrier per iteration; 4 blocks/CU.
// R7 deltas: (a) row-sums via ones-MFMA (no VALU adds, no epilogue
// shuffles); (b) XCD-chunked blockIdx swizzle so each XCD's L2 holds the
// K/V of only 4 heads (512 KB each) instead of round-robining all heads.
__global__ __launch_bounds__(256, 4)
void attn_kernel(const bf16* __restrict__ Qg, const bf16* __restrict__ Kg,
                 const bf16* __restrict__ Vt, bf16* __restrict__ yg) {
  // [0,18432): Ks[2][64][72]; [18432,36864): Vts[2][64*72].
  // Epilogue reuse: red = 16 KiB partials at 0; sred = 256 B at 16384.
  __shared__ __align__(16) char pool[36864];
  bf16* KsB = (bf16*)pool;
  bf16* VtsB = (bf16*)(pool + 18432);

  const int tid = threadIdx.x;
  const int wave = tid >> 6, lane = tid & 63;
  const int quad = lane >> 4, l16 = lane & 15;
  const int qh = wave & 1, kvh = wave >> 1;

  // XCD-chunked swizzle (nwg=1024, bijective): XCD k gets heads [4k,4k+4)
  const int bx0 = blockIdx.x;
  const int bx = ((bx0 & 7) << 7) | (bx0 >> 3);
  const int qt = bx & 31;                // 32 q-tiles of 64
  const int bh = bx >> 5;                // b*16 + h

  const bf16* Qb = Qg + ((size_t)bh * 2048 + qt * 64) * 64;
  const bf16* Kb = Kg + (size_t)bh * 2048 * 64;
  const bf16* Vtb = Vt + (size_t)bh * 64 * 2048;

  // Q fragments (pre-scaled by QSCALE at gemm0)
  short8 qf[2][2];
#pragma unroll
  for (int qblk = 0; qblk < 2; ++qblk)
#pragma unroll
    for (int ks = 0; ks < 2; ++ks)
      qf[qblk][ks] = *(const short8*)(
          Qb + (size_t)(qh * 32 + qblk * 16 + l16) * 64 + ks * 32 + quad * 8);

  // staging addressing (block-cooperative, coalesced global reads)
  const int kr = tid >> 3, kc = (tid & 7) * 8;
  const int vdd = tid & 63, vo = tid >> 6;
  const int voff0 = vdd * 72 + (((vo) + (vdd >> 3)) & 7) * 8;
  const int voff1 = vdd * 72 + (((vo + 4) + (vdd >> 3)) & 7) * 8;
  const bf16* Kp0 = Kb + (size_t)kr * 64 + kc;
  const bf16* Kp1 = Kb + (size_t)(kr + 32) * 64 + kc;
  const bf16* Vp0 = Vtb + (size_t)vdd * 2048 + vo * 8;
  const bf16* Vp1 = Vtb + (size_t)vdd * 2048 + (vo + 4) * 8;

  // preamble: tile0 -> buf0; tile1 -> regs
  {
    short8 a = *(const short8*)Kp0;
    short8 b = *(const short8*)Kp1;
    short8 c = *(const short8*)Vp0;
    short8 d = *(const short8*)Vp1;
    *(short8*)(KsB + kr * 72 + kc) = a;
    *(short8*)(KsB + (kr + 32) * 72 + kc) = b;
    *(short8*)(VtsB + voff0) = c;
    *(short8*)(VtsB + voff1) = d;
  }
  short8 gk0 = *(const short8*)(Kp0 + (size_t)64 * 64);
  short8 gk1 = *(const short8*)(Kp1 + (size_t)64 * 64);
  short8 gv0 = *(const short8*)(Vp0 + 64);
  short8 gv1 = *(const short8*)(Vp1 + 64);
  __syncthreads();

  f32x4 yacc[2][4];
#pragma unroll
  for (int qblk = 0; qblk < 2; ++qblk)
#pragma unroll
    for (int dblk = 0; dblk < 4; ++dblk)
      yacc[qblk][dblk] = (f32x4){0.f, 0.f, 0.f, 0.f};
  f32x4 sum_acc[2];
  sum_acc[0] = (f32x4){0.f, 0.f, 0.f, 0.f};
  sum_acc[1] = (f32x4){0.f, 0.f, 0.f, 0.f};

  uint4 ones_u;
  ones_u.x = ones_u.y = ones_u.z = ones_u.w = 0x3F803F80u;  // bf16 1.0 x8
  const short8 ones8 = __builtin_bit_cast(short8, ones_u);

  // per-wave fragment LDS offsets (element units)
  const int kfo = (kvh * 32 + l16) * 72 + quad * 8;    // + kvblk*16*72 + ks*32
  int vbo[4][2];                                        // b64 reads, pi-permuted
#pragma unroll
  for (int dblk = 0; dblk < 4; ++dblk) {
    const int d = dblk * 16 + l16;
#pragma unroll
    for (int kvblk = 0; kvblk < 2; ++kvblk) {
      const int c = kvh * 4 + kvblk * 2 + (quad >> 1); // t-chunk 0..7
      vbo[dblk][kvblk] = d * 72 + ((c + (d >> 3)) & 7) * 8 + (quad & 1) * 4;
    }
  }

  for (int kt = 0; kt < 2048; kt += 64) {
    const int cur = (kt >> 6) & 1;
    bf16* KsC = KsB + cur * 4608;
    bf16* VtsC = VtsB + cur * 4608;

    // 1. commit tile kt+64 into the other buffer; prefetch tile kt+128
    if (kt + 64 < 2048) {
      bf16* KsN = KsB + (cur ^ 1) * 4608;
      bf16* VtsN = VtsB + (cur ^ 1) * 4608;
      *(short8*)(KsN + kr * 72 + kc) = gk0;
      *(short8*)(KsN + (kr + 32) * 72 + kc) = gk1;
      *(short8*)(VtsN + voff0) = gv0;
      *(short8*)(VtsN + voff1) = gv1;
      if (kt + 128 < 2048) {
        gk0 = *(const short8*)(Kp0 + (size_t)(kt + 128) * 64);
        gk1 = *(const short8*)(Kp1 + (size_t)(kt + 128) * 64);
        gv0 = *(const short8*)(Vp0 + kt + 128);
        gv1 = *(const short8*)(Vp1 + kt + 128);
      }
    }

    // 2. K fragments for this wave's kv-half
    short8 kf[2][2];
#pragma unroll
    for (int kvblk = 0; kvblk < 2; ++kvblk)
#pragma unroll
      for (int ks = 0; ks < 2; ++ks)
        kf[kvblk][ks] =
            *(const short8*)(KsC + kfo + kvblk * 16 * 72 + ks * 32);

    // 3. S^T + softmax -> pa8; row-sum via ones-MFMA (no VALU adds)
    short8 pa8[2];
#pragma unroll
    for (int qblk = 0; qblk < 2; ++qblk) {
      f32x4 s0 = (f32x4){0.f, 0.f, 0.f, 0.f};
      f32x4 s1 = (f32x4){0.f, 0.f, 0.f, 0.f};
      s0 = __builtin_amdgcn_mfma_f32_16x16x32_bf16(kf[0][0], qf[qblk][0], s0, 0, 0, 0);
      s0 = __builtin_amdgcn_mfma_f32_16x16x32_bf16(kf[0][1], qf[qblk][1], s0, 0, 0, 0);
      s1 = __builtin_amdgcn_mfma_f32_16x16x32_bf16(kf[1][0], qf[qblk][0], s1, 0, 0, 0);
      s1 = __builtin_amdgcn_mfma_f32_16x16x32_bf16(kf[1][1], qf[qblk][1], s1, 0, 0, 0);
      float p0 = fast_exp2(s0[0]), p1 = fast_exp2(s0[1]);
      float p2 = fast_exp2(s0[2]), p3 = fast_exp2(s0[3]);
      float p4 = fast_exp2(s1[0]), p5 = fast_exp2(s1[1]);
      float p6 = fast_exp2(s1[2]), p7 = fast_exp2(s1[3]);
      uint4 u;
      u.x = pack2_bf16(p0, p1);
      u.y = pack2_bf16(p2, p3);
      u.z = pack2_bf16(p4, p5);
      u.w = pack2_bf16(p6, p7);
      pa8[qblk] = __builtin_bit_cast(short8, u);
      sum_acc[qblk] = __builtin_amdgcn_mfma_f32_16x16x32_bf16(
          pa8[qblk], ones8, sum_acc[qblk], 0, 0, 0);
    }

    // 4. Y += P·V, K=32 MFMA with pi-permuted V fragments (two b64 each)
#pragma unroll
    for (int dblk = 0; dblk < 4; ++dblk) {
      uint2 lo = *(const uint2*)(VtsC + vbo[dblk][0]);
      uint2 hi = *(const uint2*)(VtsC + vbo[dblk][1]);
      uint4 u;
      u.x = lo.x; u.y = lo.y; u.z = hi.x; u.w = hi.y;
      short8 vb8 = __builtin_bit_cast(short8, u);
      yacc[0][dblk] = __builtin_amdgcn_mfma_f32_16x16x32_bf16(
          pa8[0], vb8, yacc[0][dblk], 0, 0, 0);
      yacc[1][dblk] = __builtin_amdgcn_mfma_f32_16x16x32_bf16(
          pa8[1], vb8, yacc[1][dblk], 0, 0, 0);
    }

    // 5. single barrier: this iter's reads done before next iter's commits
    lds_barrier();
  }

  // ---- epilogue: reduce kv-halves across waves (sums ride in sum_acc) ----
  __syncthreads();   // all waves done with K/V LDS before scratch overwrites
  float* red = (float*)pool;                 // 16384 B Y-partials
  float* sred = (float*)(pool + 16384);      // 256 B sums
  if (kvh == 1) {
#pragma unroll
    for (int qblk = 0; qblk < 2; ++qblk) {
#pragma unroll
      for (int dblk = 0; dblk < 4; ++dblk) {
        const int f = (qh * 2 + qblk) * 4 + dblk;
        *(f32x4*)&red[(f * 64 + quad * 16 + l16) * 4] = yacc[qblk][dblk];
      }
      if (l16 == 0)
        *(f32x4*)&sred[(qh * 2 + qblk) * 16 + quad * 4] = sum_acc[qblk];
    }
  }
  __syncthreads();
  if (kvh == 0) {
    const int b = bh >> 4, h = bh & 15;
    const size_t rowbase = (size_t)b * 2048 + qt * 64;
#pragma unroll
    for (int qblk = 0; qblk < 2; ++qblk) {
      f32x4 sp = *(const f32x4*)&sred[(qh * 2 + qblk) * 16 + quad * 4];
#pragma unroll
      for (int dblk = 0; dblk < 4; ++dblk) {
        const int f = (qh * 2 + qblk) * 4 + dblk;
        f32x4 o = *(const f32x4*)&red[(f * 64 + quad * 16 + l16) * 4];
#pragma unroll
        for (int r = 0; r < 4; ++r) yacc[qblk][dblk][r] += o[r];
      }
#pragma unroll
      for (int r = 0; r < 4; ++r) {
        const float inv = 1.f / (sum_acc[qblk][r] + sp[r]);
        const int rr = qh * 32 + qblk * 16 + quad * 4 + r;
#pragma unroll
        for (int dblk = 0; dblk < 4; ++dblk)
          yg[(rowbase + rr) * 1024 + h * 64 + dblk * 16 + l16] =
              __float2bfloat16(yacc[qblk][dblk][r] * inv);
      }
    }
  }
}

// ---------------- launch ----------------
extern "C" void kernel_launch(void* const* d_in, const int* in_sizes, int n_in,
                              void* d_out, int out_size, void* d_ws, size_t ws_size,
                              hipStream_t stream) {
  const float* x = (const float*)d_in[0];      // [4096, 1024] fp32
  const float* Wqkv = (const float*)d_in[1];   // [1024, 3072] fp32
  const float* bqkv = (const float*)d_in[2];   // [3072] fp32
  const float* Wproj = (const float*)d_in[3];  // [1024, 1024] fp32
  const float* bproj = (const float*)d_in[4];  // [1024] fp32
  float* out = (float*)d_out;                  // [4096, 1024] fp32

  if (ws_size < (size_t)40 * 1024 * 1024) return;

  char* ws = (char*)d_ws;
  bf16* xb    = (bf16*)(ws + 0);             // [4096,1024] = 8 MiB
  bf16* yd    = (bf16*)(ws + 0);             // aliases xb (dead after gemm0)
  bf16* WtQkv = (bf16*)(ws + 8388608);       // [3072,1024] = 6 MiB
  bf16* WtP   = (bf16*)(ws + 14680064);      // [1024,1024] = 2 MiB
  bf16* Qd    = (bf16*)(ws + 16777216);      // [32,2048,64] = 8 MiB (pre-scaled)
  bf16* Kd    = (bf16*)(ws + 25165824);      // 8 MiB
  bf16* Vten  = (bf16*)(ws + 33554432);      // [32,64,2048] = 8 MiB

  prep_k<<<3072, 256, 0, stream>>>(x, xb, Wqkv, WtQkv, Wproj, WtP);
  gemm_bt<0, 128><<<dim3(24, 32), 256, 0, stream>>>(
      xb, WtQkv, bqkv, nullptr, Qd, Kd, Vten, 4096, 3072, 1024);
  attn_kernel<<<dim3(1024), 256, 0, stream>>>(Qd, Kd, Vten, yd);
  gemm_bt<1, 64><<<dim3(8, 64), 256, 0, stream>>>(
      yd, WtP, bproj, out, nullptr, nullptr, nullptr, 4096, 1024, 1024);
}

// Round 8
// 186.506 us; speedup vs baseline: 1.2306x; 1.0318x over previous
//
#include <hip/hip_runtime.h>
#include <hip/hip_bf16.h>
#include <stdint.h>

typedef __hip_bfloat16 bf16;
typedef __attribute__((ext_vector_type(8))) short short8;   // 8 bf16
typedef __attribute__((ext_vector_type(4))) float f32x4;

#define QSCALE 0.18033688011f   // 0.125 * log2(e), folded into Q at gemm0

// ---- 1-instr helpers ----
__device__ __forceinline__ float fast_exp2(float x) {
#if __has_builtin(__builtin_amdgcn_exp2f)
  return __builtin_amdgcn_exp2f(x);
#else
  return exp2f(x);
#endif
}

__device__ __forceinline__ uint32_t pack2_bf16(float a, float b) {
#if __has_builtin(__builtin_amdgcn_cvt_pk_bf16_f32)
  typedef __attribute__((ext_vector_type(2))) __bf16 bf16x2;
  bf16x2 v = __builtin_amdgcn_cvt_pk_bf16_f32(a, b);
  return __builtin_bit_cast(uint32_t, v);
#else
  uint32_t ua = __builtin_bit_cast(uint32_t, a);
  uint32_t ub = __builtin_bit_cast(uint32_t, b);
  ua += 0x7FFF + ((ua >> 16) & 1);   // RNE
  ub += 0x7FFF + ((ub >> 16) & 1);
  return (ua >> 16) | (ub & 0xFFFF0000u);
#endif
}

// async global->LDS, 16B per lane: g is the PER-LANE global pointer,
// l is the WAVE-UNIFORM LDS base (lane lands at l + lane*16B).
__device__ __forceinline__ void gload_lds16(const bf16* g, bf16* l) {
#if __has_builtin(__builtin_amdgcn_global_load_lds)
  __builtin_amdgcn_global_load_lds(
      (const __attribute__((address_space(1))) void*)(uintptr_t)g,
      (__attribute__((address_space(3))) void*)(uint32_t)(uintptr_t)l,
      16, 0, 0);
#else
  int lane = threadIdx.x & 63;
  *(short8*)(l + lane * 8) = *(const short8*)(g + lane * 8);
#endif
}

// ---- fp32->bf16 transpose tile body (64x64) ----
__device__ __forceinline__ void transpose_tile(const float* __restrict__ in,
                                               bf16* __restrict__ out,
                                               int R, int C, int bx, int by,
                                               bf16 (*t)[72]) {
  const int r0 = by * 64, c0 = bx * 64;
  const int rr = threadIdx.x >> 3, cc = (threadIdx.x & 7) * 8;
#pragma unroll
  for (int rep = 0; rep < 2; ++rep) {
    int y = rr + rep * 32;
    const float* p = in + (size_t)(r0 + y) * C + c0 + cc;
    f32x4 v0 = *(const f32x4*)p;
    f32x4 v1 = *(const f32x4*)(p + 4);
#pragma unroll
    for (int j = 0; j < 4; ++j) {
      t[cc + j][y] = __float2bfloat16(v0[j]);
      t[cc + 4 + j][y] = __float2bfloat16(v1[j]);
    }
  }
  __syncthreads();
#pragma unroll
  for (int rep = 0; rep < 2; ++rep) {
    int y = rr + rep * 32;
    short8 v = *(const short8*)&t[y][cc];
    *(short8*)(out + (size_t)(c0 + y) * R + r0 + cc) = v;
  }
}

// ---- fused prep: x->bf16 (blocks 0..2047), Wqkv^T (2048..2815),
//      Wproj^T (2816..3071) ----
__global__ __launch_bounds__(256)
void prep_k(const float* __restrict__ x, bf16* __restrict__ xb,
            const float* __restrict__ Wqkv, bf16* __restrict__ WtQkv,
            const float* __restrict__ Wproj, bf16* __restrict__ WtP) {
  __shared__ __align__(16) bf16 t[64][72];
  const int bid = blockIdx.x;
  if (bid < 2048) {
    int i = (bid * 256 + threadIdx.x) * 8;
    f32x4 v0 = *(const f32x4*)(x + i);
    f32x4 v1 = *(const f32x4*)(x + i + 4);
    short8 r;
    bf16* rb = (bf16*)&r;
#pragma unroll
    for (int j = 0; j < 4; ++j) {
      rb[j] = __float2bfloat16(v0[j]);
      rb[4 + j] = __float2bfloat16(v1[j]);
    }
    *(short8*)(xb + i) = r;
  } else if (bid < 2048 + 768) {
    int b = bid - 2048;
    transpose_tile(Wqkv, WtQkv, 1024, 3072, b % 48, b / 48, t);
  } else {
    int b = bid - 2816;
    transpose_tile(Wproj, WtP, 1024, 1024, b % 16, b / 16, t);
  }
}

// ---------------- GEMM: C[m][n] = A[m,:]·Bt[n,:] + bias[n] -------------------
// MODE 0 (TM=128): LDS-transposed coalesced epilogue -> Q (xQSCALE) as
//   [bh][t][64] (linear), K as [bh][t][64] with 16B-chunk XOR-swizzle
//   (chunk ^= row&7), V^T as [bh][64][t] with per-64-tile chunk XOR-swizzle
//   (chunk ^= d&7). The swizzles let attn stage K/V LINEARLY via
//   global_load_lds and read fragments conflict-free (rule: pre-swizzled
//   source + linear DMA + swizzled read).
// MODE 1 (TM=64): fp32 out row-major [M,Nn].
// Grid XCD-chunk swizzled (nwg % 8 == 0 -> bijective). MODE 0 runs at
// 3 blocks/CU (768 = 3x256, zero tail, m97-matching occupancy).
template <int MODE, int TM>
__global__ __launch_bounds__(256, (TM == 128) ? 3 : 2)
void gemm_bt(const bf16* __restrict__ A, const bf16* __restrict__ Bt,
             const float* __restrict__ bias, float* __restrict__ outp,
             bf16* __restrict__ Qd, bf16* __restrict__ Kd, bf16* __restrict__ Vt,
             int M, int Nn, int K) {
  constexpr int MI = TM / 32;
  // staging (TM*32 + 4096 el) and MODE-0 epilogue (<=9216 el) share this pool
  __shared__ __align__(16) bf16 smem[(TM == 128) ? 9216 : 6144];
  bf16* As = smem;
  bf16* Bs = smem + TM * 32;

  const int tid = threadIdx.x;
  const int wave = tid >> 6, lane = tid & 63;
  const int quad = lane >> 4, l16 = lane & 15;
  const int mw = (wave >> 1) * (TM / 2), nw = (wave & 1) * 64;

  // XCD-chunked swizzle of the linearized block id
  const int nwg = gridDim.x * gridDim.y;
  const int ord = blockIdx.y * gridDim.x + blockIdx.x;
  const int wg = (ord & 7) * (nwg >> 3) + (ord >> 3);
  const int m_blk = (wg / gridDim.x) * TM, n_blk = (wg % gridDim.x) * 128;

  f32x4 acc[MI][4];
#pragma unroll
  for (int i = 0; i < MI; ++i)
#pragma unroll
    for (int j = 0; j < 4; ++j) acc[i][j] = (f32x4){0.f, 0.f, 0.f, 0.f};

  const int rowA = lane >> 2, colA = (lane & 3) * 8;
  const int chunkB = wave * 2;
  const bf16* gB = Bt + (size_t)(n_blk + chunkB * 16 + rowA) * K + colA;
  bf16* lB0 = &Bs[chunkB * 16 * 32];
  bf16* lB1 = &Bs[(chunkB + 1) * 16 * 32];

  const int chunkA = (TM == 128) ? wave * 2 : wave;
  const bf16* gA = A + (size_t)(m_blk + chunkA * 16 + rowA) * K + colA;
  bf16* lA0 = &As[chunkA * 16 * 32];
  bf16* lA1 = &As[(chunkA + 1) * 16 * 32];  // unused for TM=64

  for (int kt = 0; kt < K; kt += 32) {
    gload_lds16(gA, lA0);
    if (TM == 128) gload_lds16(gA + 16 * K, lA1);
    gload_lds16(gB, lB0);
    gload_lds16(gB + 16 * K, lB1);
    gA += 32; gB += 32;
    __syncthreads();
    short8 af[MI], bfv[4];
#pragma unroll
    for (int i = 0; i < MI; ++i)
      af[i] = *(const short8*)&As[(mw + i * 16 + l16) * 32 + quad * 8];
#pragma unroll
    for (int j = 0; j < 4; ++j)
      bfv[j] = *(const short8*)&Bs[(nw + j * 16 + l16) * 32 + quad * 8];
#pragma unroll
    for (int i = 0; i < MI; ++i)
#pragma unroll
      for (int j = 0; j < 4; ++j)
        acc[i][j] = __builtin_amdgcn_mfma_f32_16x16x32_bf16(af[i], bfv[j],
                                                            acc[i][j], 0, 0, 0);
    __syncthreads();
  }

  if (MODE == 0) {
    // per-j bias for this wave's columns
    float bval[4];
#pragma unroll
    for (int j = 0; j < 4; ++j) bval[j] = bias[n_blk + nw + j * 16 + l16];

    const int part = n_blk >> 10;          // 0:q 1:k 2:v (block-uniform)
    const int b = m_blk >> 11;
    const int tloc = m_blk & 2047;
    const int h0 = (n_blk & 1023) >> 6;

#pragma unroll
    for (int p = 0; p < 2; ++p) {          // feature halves (64 cols = 1 head)
      __syncthreads();
      if ((nw >> 6) == p) {
        if (part == 2) {
          // V half-tile as [64 d][136 t], 8B-packed writes (r -> t contiguous)
#pragma unroll
          for (int i = 0; i < MI; ++i)
#pragma unroll
            for (int j = 0; j < 4; ++j) {
              const int dh = j * 16 + l16;
              const int t0 = mw + i * 16 + quad * 4;
              uint2 pk;
              pk.x = pack2_bf16(acc[i][j][0] + bval[j], acc[i][j][1] + bval[j]);
              pk.y = pack2_bf16(acc[i][j][2] + bval[j], acc[i][j][3] + bval[j]);
              *(uint2*)&smem[dh * 136 + t0] = pk;
            }
        } else {
          // Q/K half-tile as [128 t][72 d] (stride-72: conflict-free writes)
          const float sc = (part == 0) ? QSCALE : 1.0f;
#pragma unroll
          for (int i = 0; i < MI; ++i)
#pragma unroll
            for (int j = 0; j < 4; ++j) {
              const int d = j * 16 + l16;
              const int t0 = mw + i * 16 + quad * 4;
#pragma unroll
              for (int r = 0; r < 4; ++r)
                smem[(t0 + r) * 72 + d] =
                    __float2bfloat16((acc[i][j][r] + bval[j]) * sc);
            }
        }
      }
      __syncthreads();
      const size_t bh = (size_t)(b * 16 + h0 + p);
      if (part == 2) {
        // store with per-64-tile chunk swizzle: chunk ^= (d & 7)
#pragma unroll
        for (int it = 0; it < 4; ++it) {
          const int dl = (tid >> 4) + it * 16;
          const int t8 = (tid & 15) * 8;
          const int t8s = (t8 & 64) | ((t8 ^ ((dl & 7) << 3)) & 63);
          short8 v = *(const short8*)&smem[dl * 136 + t8];
          *(short8*)&Vt[(bh * 64 + dl) * 2048 + tloc + t8s] = v;
        }
      } else {
        bf16* dst = (part == 0) ? Qd : Kd;
#pragma unroll
        for (int it = 0; it < 4; ++it) {
          const int row = (tid >> 3) + it * 32;
          const int col8 = (tid & 7) * 8;
          // K gets the 16B-chunk XOR swizzle; Q stays linear
          const int c8 = (part == 1) ? (col8 ^ ((row & 7) << 3)) : col8;
          short8 v = *(const short8*)&smem[row * 72 + col8];
          *(short8*)&dst[(bh * 2048 + tloc + row) * 64 + c8] = v;
        }
      }
    }
  } else {
#pragma unroll
    for (int j = 0; j < 4; ++j) {
      const int ncol = n_blk + nw + j * 16 + l16;
      const float bval = bias[ncol];
#pragma unroll
      for (int i = 0; i < MI; ++i) {
        const int mrow0 = m_blk + mw + i * 16 + quad * 4;
#pragma unroll
        for (int r = 0; r < 4; ++r)
          outp[(size_t)(mrow0 + r) * Nn + ncol] = acc[i][j][r] + bval;
      }
    }
  }
}

// ---------------- flash attention: Qtile=64, KVtile=64, quadrant split -------
// R3/R7 structure (best measured) with the staging path converted to async
// global_load_lds: K/V arrive pre-XOR-swizzled from gemm0, are DMA'd LINEARLY
// into [64][64] LDS tiles (4 gload_lds/wave/iter, no reg round-trip, no
// ds_writes), and fragment reads apply the same XOR -> conflict-free.
// Barrier = vmcnt(0) lgkmcnt(0) + s_barrier once per iter; loads issued at
// iter start have the full iteration to land. P stays in registers via the
// pi-permuted K=32 PV; row-sums via ones-MFMA. 32768 B LDS -> 4 blocks/CU.
__global__ __launch_bounds__(256, 4)
void attn_kernel(const bf16* __restrict__ Qg, const bf16* __restrict__ Kg,
                 const bf16* __restrict__ Vt, bf16* __restrict__ yg) {
  // [0,16384): Ks[2][64][64]; [16384,32768): Vts[2][64][64].
  // Epilogue reuse: red = 16 KiB partials at 0; sred = 256 B at 16384.
  __shared__ __align__(16) char pool[32768];
  bf16* KsB = (bf16*)pool;
  bf16* VtsB = (bf16*)(pool + 16384);

  const int tid = threadIdx.x;
  const int wave = tid >> 6, lane = tid & 63;
  const int quad = lane >> 4, l16 = lane & 15;
  const int qh = wave & 1, kvh = wave >> 1;

  // XCD-chunked swizzle (nwg=1024, bijective): XCD k gets heads [4k,4k+4)
  const int bx0 = blockIdx.x;
  const int bx = ((bx0 & 7) << 7) | (bx0 >> 3);
  const int qt = bx & 31;                // 32 q-tiles of 64
  const int bh = bx >> 5;                // b*16 + h

  const bf16* Qb = Qg + ((size_t)bh * 2048 + qt * 64) * 64;
  const bf16* Kb = Kg + (size_t)bh * 2048 * 64;
  const bf16* Vtb = Vt + (size_t)bh * 64 * 2048;

  // Q fragments (linear layout, pre-scaled by QSCALE at gemm0)
  short8 qf[2][2];
#pragma unroll
  for (int qblk = 0; qblk < 2; ++qblk)
#pragma unroll
    for (int ks = 0; ks < 2; ++ks)
      qf[qblk][ks] = *(const short8*)(
          Qb + (size_t)(qh * 32 + qblk * 16 + l16) * 64 + ks * 32 + quad * 8);

  // async staging pointers: wave w issues instrs j=0,1 per tensor.
  // K tile kt is 8 KB contiguous at Kb + kt*64 (swizzled rows, copied
  // verbatim). V tile: per-lane source d=(2w+j)*8+(lane>>3), t'=(lane&7)*8.
  const int sj = wave * 2;
  const bf16* kg = Kb + sj * 512 + lane * 8;                       // +kt*64+j*512
  const bf16* vg = Vtb + (size_t)(sj * 8 + (lane >> 3)) * 2048 +
                   (lane & 7) * 8;                                  // +kt+j*16384

  // fragment read offsets (XOR de-swizzle; all conflict-free)
  int kfo[2][2];
#pragma unroll
  for (int kvblk = 0; kvblk < 2; ++kvblk)
#pragma unroll
    for (int ks = 0; ks < 2; ++ks)
      kfo[kvblk][ks] = (kvh * 32 + kvblk * 16 + l16) * 64 +
                       (((ks * 4 + quad) ^ (l16 & 7)) << 3);
  int vbo[4][2];
#pragma unroll
  for (int dblk = 0; dblk < 4; ++dblk) {
    const int d = dblk * 16 + l16;
#pragma unroll
    for (int kvblk = 0; kvblk < 2; ++kvblk) {
      const int ct = kvh * 4 + kvblk * 2 + (quad >> 1);  // logical t-chunk
      vbo[dblk][kvblk] = d * 64 + ((ct ^ (d & 7)) << 3) + (quad & 1) * 4;
    }
  }

  // preamble: DMA tile 0 -> buf0
#pragma unroll
  for (int j = 0; j < 2; ++j) {
    gload_lds16(kg + j * 512, KsB + sj * 512 + j * 512);
    gload_lds16(vg + (size_t)j * 16384, VtsB + sj * 512 + j * 512);
  }
  asm volatile("s_waitcnt vmcnt(0) lgkmcnt(0)\n\ts_barrier" ::: "memory");

  f32x4 yacc[2][4];
#pragma unroll
  for (int qblk = 0; qblk < 2; ++qblk)
#pragma unroll
    for (int dblk = 0; dblk < 4; ++dblk)
      yacc[qblk][dblk] = (f32x4){0.f, 0.f, 0.f, 0.f};
  f32x4 sum_acc[2];
  sum_acc[0] = (f32x4){0.f, 0.f, 0.f, 0.f};
  sum_acc[1] = (f32x4){0.f, 0.f, 0.f, 0.f};

  uint4 ones_u;
  ones_u.x = ones_u.y = ones_u.z = ones_u.w = 0x3F803F80u;  // bf16 1.0 x8
  const short8 ones8 = __builtin_bit_cast(short8, ones_u);

  for (int kt = 0; kt < 2048; kt += 64) {
    const int cur = (kt >> 6) & 1;

    // 1. issue DMA for tile kt+64 into the other buffer (hidden under compute)
    if (kt + 64 < 2048) {
      bf16* Kd = KsB + (cur ^ 1) * 4096;
      bf16* Vd = VtsB + (cur ^ 1) * 4096;
#pragma unroll
      for (int j = 0; j < 2; ++j) {
        gload_lds16(kg + (kt + 64) * 64 + j * 512, Kd + sj * 512 + j * 512);
        gload_lds16(vg + kt + 64 + (size_t)j * 16384, Vd + sj * 512 + j * 512);
      }
    }
    const bf16* KsC = KsB + cur * 4096;
    const bf16* VtsC = VtsB + cur * 4096;

    // 2. K fragments for this wave's kv-half
    short8 kf[2][2];
#pragma unroll
    for (int kvblk = 0; kvblk < 2; ++kvblk)
#pragma unroll
      for (int ks = 0; ks < 2; ++ks)
        kf[kvblk][ks] = *(const short8*)(KsC + kfo[kvblk][ks]);

    // 3. S^T + softmax -> pa8; row-sum via ones-MFMA (no VALU adds)
    short8 pa8[2];
#pragma unroll
    for (int qblk = 0; qblk < 2; ++qblk) {
      f32x4 s0 = (f32x4){0.f, 0.f, 0.f, 0.f};
      f32x4 s1 = (f32x4){0.f, 0.f, 0.f, 0.f};
      s0 = __builtin_amdgcn_mfma_f32_16x16x32_bf16(kf[0][0], qf[qblk][0], s0, 0, 0, 0);
      s0 = __builtin_amdgcn_mfma_f32_16x16x32_bf16(kf[0][1], qf[qblk][1], s0, 0, 0, 0);
      s1 = __builtin_amdgcn_mfma_f32_16x16x32_bf16(kf[1][0], qf[qblk][0], s1, 0, 0, 0);
      s1 = __builtin_amdgcn_mfma_f32_16x16x32_bf16(kf[1][1], qf[qblk][1], s1, 0, 0, 0);
      float p0 = fast_exp2(s0[0]), p1 = fast_exp2(s0[1]);
      float p2 = fast_exp2(s0[2]), p3 = fast_exp2(s0[3]);
      float p4 = fast_exp2(s1[0]), p5 = fast_exp2(s1[1]);
      float p6 = fast_exp2(s1[2]), p7 = fast_exp2(s1[3]);
      uint4 u;
      u.x = pack2_bf16(p0, p1);
      u.y = pack2_bf16(p2, p3);
      u.z = pack2_bf16(p4, p5);
      u.w = pack2_bf16(p6, p7);
      pa8[qblk] = __builtin_bit_cast(short8, u);
      sum_acc[qblk] = __builtin_amdgcn_mfma_f32_16x16x32_bf16(
          pa8[qblk], ones8, sum_acc[qblk], 0, 0, 0);
    }

    // 4. Y += P·V, K=32 MFMA with pi-permuted V fragments (two b64 each)
#pragma unroll
    for (int dblk = 0; dblk < 4; ++dblk) {
      uint2 lo = *(const uint2*)(VtsC + vbo[dblk][0]);
      uint2 hi = *(const uint2*)(VtsC + vbo[dblk][1]);
      uint4 u;
      u.x = lo.x; u.y = lo.y; u.z = hi.x; u.w = hi.y;
      short8 vb8 = __builtin_bit_cast(short8, u);
      yacc[0][dblk] = __builtin_amdgcn_mfma_f32_16x16x32_bf16(
          pa8[0], vb8, yacc[0][dblk], 0, 0, 0);
      yacc[1][dblk] = __builtin_amdgcn_mfma_f32_16x16x32_bf16(
          pa8[1], vb8, yacc[1][dblk], 0, 0, 0);
    }

    // 5. single barrier: DMA for kt+64 landed + this iter's LDS reads done
    asm volatile("s_waitcnt vmcnt(0) lgkmcnt(0)\n\ts_barrier" ::: "memory");
  }

  // ---- epilogue: reduce kv-halves across waves (sums ride in sum_acc) ----
  __syncthreads();   // all waves done with K/V LDS before scratch overwrites
  float* red = (float*)pool;                 // 16384 B Y-partials
  float* sred = (float*)(pool + 16384);      // 256 B sums
  if (kvh == 1) {
#pragma unroll
    for (int qblk = 0; qblk < 2; ++qblk) {
#pragma unroll
      for (int dblk = 0; dblk < 4; ++dblk) {
        const int f = (qh * 2 + qblk) * 4 + dblk;
        *(f32x4*)&red[(f * 64 + quad * 16 + l16) * 4] = yacc[qblk][dblk];
      }
      if (l16 == 0)
        *(f32x4*)&sred[(qh * 2 + qblk) * 16 + quad * 4] = sum_acc[qblk];
    }
  }
  __syncthreads();
  if (kvh == 0) {
    const int b = bh >> 4, h = bh & 15;
    const size_t rowbase = (size_t)b * 2048 + qt * 64;
#pragma unroll
    for (int qblk = 0; qblk < 2; ++qblk) {
      f32x4 sp = *(const f32x4*)&sred[(qh * 2 + qblk) * 16 + quad * 4];
#pragma unroll
      for (int dblk = 0; dblk < 4; ++dblk) {
        const int f = (qh * 2 + qblk) * 4 + dblk;
        f32x4 o = *(const f32x4*)&red[(f * 64 + quad * 16 + l16) * 4];
#pragma unroll
        for (int r = 0; r < 4; ++r) yacc[qblk][dblk][r] += o[r];
      }
#pragma unroll
      for (int r = 0; r < 4; ++r) {
        const float inv = 1.f / (sum_acc[qblk][r] + sp[r]);
        const int rr = qh * 32 + qblk * 16 + quad * 4 + r;
#pragma unroll
        for (int dblk = 0; dblk < 4; ++dblk)
          yg[(rowbase + rr) * 1024 + h * 64 + dblk * 16 + l16] =
              __float2bfloat16(yacc[qblk][dblk][r] * inv);
      }
    }
  }
}

// ---------------- launch ----------------
extern "C" void kernel_launch(void* const* d_in, const int* in_sizes, int n_in,
                              void* d_out, int out_size, void* d_ws, size_t ws_size,
                              hipStream_t stream) {
  const float* x = (const float*)d_in[0];      // [4096, 1024] fp32
  const float* Wqkv = (const float*)d_in[1];   // [1024, 3072] fp32
  const float* bqkv = (const float*)d_in[2];   // [3072] fp32
  const float* Wproj = (const float*)d_in[3];  // [1024, 1024] fp32
  const float* bproj = (const float*)d_in[4];  // [1024] fp32
  float* out = (float*)d_out;                  // [4096, 1024] fp32

  if (ws_size < (size_t)40 * 1024 * 1024) return;

  char* ws = (char*)d_ws;
  bf16* xb    = (bf16*)(ws + 0);             // [4096,1024] = 8 MiB
  bf16* yd    = (bf16*)(ws + 0);             // aliases xb (dead after gemm0)
  bf16* WtQkv = (bf16*)(ws + 8388608);       // [3072,1024] = 6 MiB
  bf16* WtP   = (bf16*)(ws + 14680064);      // [1024,1024] = 2 MiB
  bf16* Qd    = (bf16*)(ws + 16777216);      // [32,2048,64] = 8 MiB (pre-scaled)
  bf16* Kd    = (bf16*)(ws + 25165824);      // 8 MiB (chunk-swizzled rows)
  bf16* Vten  = (bf16*)(ws + 33554432);      // [32,64,2048] = 8 MiB (swizzled)

  prep_k<<<3072, 256, 0, stream>>>(x, xb, Wqkv, WtQkv, Wproj, WtP);
  gemm_bt<0, 128><<<dim3(24, 32), 256, 0, stream>>>(
      xb, WtQkv, bqkv, nullptr, Qd, Kd, Vten, 4096, 3072, 1024);
  attn_kernel<<<dim3(1024), 256, 0, stream>>>(Qd, Kd, Vten, yd);
  gemm_bt<1, 64><<<dim3(8, 64), 256, 0, stream>>>(
      yd, WtP, bproj, out, nullptr, nullptr, nullptr, 4096, 1024, 1024);
}